// Round 1
// baseline (284.783 us; speedup 1.0000x reference)
//
#include <hip/hip_runtime.h>
#include <math.h>

#define BQ     4
#define QN     256
#define KN     1024
#define DIN    256     // Q_SIZE == K_SIZE == V_SIZE
#define HD     128     // H
#define NEGV   -1000000.0f

// ---------------- projection: out[row,h] = dot(x[row,:], W[h,:]) ----------------
// grid = num_rows blocks, 128 threads (one per h)
__global__ __launch_bounds__(128) void proj_kernel(const float* __restrict__ x,
                                                   const float* __restrict__ W,
                                                   float* __restrict__ out) {
    const int blk = blockIdx.x;
    const int h = threadIdx.x;
    __shared__ float xrow[DIN];
    const float* xr = x + (size_t)blk * DIN;
    xrow[h]       = xr[h];
    xrow[h + 128] = xr[h + 128];
    __syncthreads();
    const float* w = W + (size_t)h * DIN;
    float acc = 0.f;
#pragma unroll 8
    for (int i = 0; i < DIN; i += 4) {
        float4 wv = *(const float4*)(w + i);
        acc += wv.x * xrow[i]     + wv.y * xrow[i + 1]
             + wv.z * xrow[i + 2] + wv.w * xrow[i + 3];
    }
    out[(size_t)blk * HD + h] = acc;
}

// ---------------- fused scores + softmax + attn@V ----------------
// grid = B*QN blocks (one per (b, q-row)), 256 threads
__global__ __launch_bounds__(256) void attn_kernel(const float* __restrict__ qp,
                                                   const float* __restrict__ kp,
                                                   const float* __restrict__ values,
                                                   const int* __restrict__ valid_lens,
                                                   const float* __restrict__ w_v,
                                                   float* __restrict__ out) {
    const int blk = blockIdx.x;          // b*QN + qrow
    const int b = blk >> 8;              // / QN
    const int t = threadIdx.x;

    __shared__ float s_qp[HD];
    __shared__ float s_wv[HD];
    __shared__ float s_sc[KN];
    __shared__ float s_red[8];

    if (t < HD) {
        s_qp[t] = qp[(size_t)blk * HD + t];
        s_wv[t] = w_v[t];
    }
    __syncthreads();

    const int valid = valid_lens[b];
    const float* kpb = kp + (size_t)b * KN * HD;

    // ---- scores: s[k] = sum_h w_v[h] * tanh(qp[h] + kp[k,h]) ----
    for (int k = t; k < KN; k += 256) {
        float acc = NEGV;
        if (k < valid) {
            acc = 0.f;
            const float* kr = kpb + (size_t)k * HD;
#pragma unroll
            for (int h = 0; h < HD; h += 4) {
                float4 kv = *(const float4*)(kr + h);
                acc += s_wv[h]     * tanhf(s_qp[h]     + kv.x);
                acc += s_wv[h + 1] * tanhf(s_qp[h + 1] + kv.y);
                acc += s_wv[h + 2] * tanhf(s_qp[h + 2] + kv.z);
                acc += s_wv[h + 3] * tanhf(s_qp[h + 3] + kv.w);
            }
        }
        s_sc[k] = acc;
    }
    __syncthreads();

    // ---- softmax over k < valid (invalid cols get exactly 0 weight, matching
    //      the reference where exp(-1e6 - m) underflows to 0) ----
    const int wave = t >> 6, lane = t & 63;

    float lmax = -INFINITY;
    for (int k = t; k < valid; k += 256) lmax = fmaxf(lmax, s_sc[k]);
#pragma unroll
    for (int off = 32; off > 0; off >>= 1) lmax = fmaxf(lmax, __shfl_down(lmax, off, 64));
    if (lane == 0) s_red[wave] = lmax;
    __syncthreads();
    if (t == 0)
        s_red[4] = fmaxf(fmaxf(s_red[0], s_red[1]), fmaxf(s_red[2], s_red[3]));
    __syncthreads();
    const float m = s_red[4];

    float lsum = 0.f;
    for (int k = t; k < valid; k += 256) {
        float e = __expf(s_sc[k] - m);
        s_sc[k] = e;
        lsum += e;
    }
#pragma unroll
    for (int off = 32; off > 0; off >>= 1) lsum += __shfl_down(lsum, off, 64);
    if (lane == 0) s_red[wave] = lsum;
    __syncthreads();
    if (t == 0) s_red[5] = s_red[0] + s_red[1] + s_red[2] + s_red[3];
    __syncthreads();
    const float inv = 1.0f / s_red[5];

    // ---- out[v] = inv * sum_{k<valid} e[k] * values[b,k,v] ; v = t ----
    const float* vb = values + (size_t)b * KN * DIN + t;
    float acc = 0.f;
    int k = 0;
    for (; k + 4 <= valid; k += 4) {
        acc += s_sc[k]     * vb[(size_t)k       * DIN];
        acc += s_sc[k + 1] * vb[(size_t)(k + 1) * DIN];
        acc += s_sc[k + 2] * vb[(size_t)(k + 2) * DIN];
        acc += s_sc[k + 3] * vb[(size_t)(k + 3) * DIN];
    }
    for (; k < valid; k++) acc += s_sc[k] * vb[(size_t)k * DIN];
    out[(size_t)blk * DIN + t] = acc * inv;
}

extern "C" void kernel_launch(void* const* d_in, const int* in_sizes, int n_in,
                              void* d_out, int out_size, void* d_ws, size_t ws_size,
                              hipStream_t stream) {
    const float* queries    = (const float*)d_in[0];  // [B,Q,256]
    const float* keys       = (const float*)d_in[1];  // [B,K,256]
    const float* values     = (const float*)d_in[2];  // [B,K,256]
    const int*   valid_lens = (const int*)d_in[3];    // [B]
    const float* W_q        = (const float*)d_in[4];  // [128,256]
    const float* W_k        = (const float*)d_in[5];  // [128,256]
    const float* w_v        = (const float*)d_in[6];  // [128]
    float* out = (float*)d_out;

    float* qp = (float*)d_ws;                                // [B*Q,128]  512 KB
    float* kp = qp + (size_t)BQ * QN * HD;                   // [B*K,128]  2 MB

    proj_kernel<<<BQ * QN, 128, 0, stream>>>(queries, W_q, qp);
    proj_kernel<<<BQ * KN, 128, 0, stream>>>(keys, W_k, kp);
    attn_kernel<<<BQ * QN, 256, 0, stream>>>(qp, kp, values, valid_lens, w_v, out);
}

// Round 2
// 190.763 us; speedup vs baseline: 1.4929x; 1.4929x over previous
//
#include <hip/hip_runtime.h>
#include <math.h>

#define BQ   4
#define QN   256
#define KN   1024
#define DIN  256     // Q_SIZE == K_SIZE == V_SIZE
#define HD   128     // H

// tanh(x) = copysign((1-e)/(1+e), x),  e = exp2(-2*log2e*|x|)
__device__ __forceinline__ float fast_tanh(float x) {
    const float c = -2.8853900817779268f;   // -2*log2(e)
    float e = __builtin_amdgcn_exp2f(c * __builtin_fabsf(x));
    float r = __builtin_amdgcn_rcpf(1.0f + e);
    float th = __builtin_fmaf(-e, r, r);    // (1-e)*r
    return __builtin_copysignf(th, x);
}

// ---------------- fused projections: 16 rows/block, 256 threads ----------------
// blocks 0..63   : q rows (queries x W_q -> qp)
// blocks 64..319 : k rows (keys x W_k -> kp)
__global__ __launch_bounds__(256) void proj_kernel(const float* __restrict__ queries,
                                                   const float* __restrict__ keys,
                                                   const float* __restrict__ W_q,
                                                   const float* __restrict__ W_k,
                                                   float* __restrict__ qp,
                                                   float* __restrict__ kp) {
    const int blk = blockIdx.x;
    const int t = threadIdx.x;
    const int h = t & 127;
    const int g = __builtin_amdgcn_readfirstlane(t >> 7);  // wave-uniform row-group

    const float* x; const float* W; float* dst; int row0;
    if (blk < (BQ * QN) / 16) {
        x = queries; W = W_q; dst = qp; row0 = blk * 16;
    } else {
        x = keys;    W = W_k; dst = kp; row0 = (blk - (BQ * QN) / 16) * 16;
    }
    row0 += g * 8;

    const float* wrow = W + (size_t)h * DIN;
    float acc[8];
#pragma unroll
    for (int j = 0; j < 8; j++) acc[j] = 0.f;

#pragma unroll 4
    for (int i = 0; i < DIN; i += 4) {
        float4 wv = *(const float4*)(wrow + i);
#pragma unroll
        for (int j = 0; j < 8; j++) {
            float4 xv = *(const float4*)(x + (size_t)(row0 + j) * DIN + i);  // uniform -> s_load
            acc[j] = __builtin_fmaf(wv.x, xv.x,
                     __builtin_fmaf(wv.y, xv.y,
                     __builtin_fmaf(wv.z, xv.z,
                     __builtin_fmaf(wv.w, xv.w, acc[j]))));
        }
    }
#pragma unroll
    for (int j = 0; j < 8; j++)
        dst[(size_t)(row0 + j) * HD + h] = acc[j];
}

// ---------------- fused scores + softmax + attn@V : 2 q-rows/block ----------------
// grid = B * QN/2 = 512 blocks, 256 threads
__global__ __launch_bounds__(256, 2) void attn_kernel(const float* __restrict__ qp,
                                                      const float* __restrict__ kp,
                                                      const float* __restrict__ values,
                                                      const int* __restrict__ valid_lens,
                                                      const float* __restrict__ w_v,
                                                      float* __restrict__ out) {
    __shared__ float s_qp[2][HD];
    __shared__ float s_wv[HD];
    __shared__ float s_sc[2][KN];      // scores, row-major (softmax passes)
    __shared__ float s_e[KN][2];       // exp'd scores, transposed (AV phase, b64 reads)
    __shared__ float s_part[4][2][DIN];
    __shared__ float s_red[4], s_sum[4], s_inv[2];

    const int blk = blockIdx.x;        // b*128 + qtile
    const int b = blk >> 7;
    const int q0 = (blk & 127) * 2;
    const int t = threadIdx.x;

    if (t < 2 * HD) s_qp[t >> 7][t & 127] = qp[(size_t)(b * QN + q0 + (t >> 7)) * HD + (t & 127)];
    if (t < HD) s_wv[t] = w_v[t];
    const int valid = valid_lens[b];
    __syncthreads();

    // ---- scores: s[q][k] = sum_h w_v[h]*tanh(qp[q][h]+kp[k][h]), only k < valid ----
    const float* kpb = kp + (size_t)b * KN * HD;
#pragma unroll
    for (int pass = 0; pass < 4; pass++) {
        int k = pass * 256 + t;
        if (k < valid) {
            const float* kr = kpb + (size_t)k * HD;
            float a0 = 0.f, a1 = 0.f;
#pragma unroll 4
            for (int h = 0; h < HD; h += 4) {
                float4 kv = *(const float4*)(kr + h);
                float w0 = s_wv[h], w1 = s_wv[h + 1], w2 = s_wv[h + 2], w3 = s_wv[h + 3];
                float p0 = s_qp[0][h], p1 = s_qp[0][h + 1], p2 = s_qp[0][h + 2], p3 = s_qp[0][h + 3];
                float u0 = s_qp[1][h], u1 = s_qp[1][h + 1], u2 = s_qp[1][h + 2], u3 = s_qp[1][h + 3];
                a0 += w0 * fast_tanh(p0 + kv.x) + w1 * fast_tanh(p1 + kv.y)
                    + w2 * fast_tanh(p2 + kv.z) + w3 * fast_tanh(p3 + kv.w);
                a1 += w0 * fast_tanh(u0 + kv.x) + w1 * fast_tanh(u1 + kv.y)
                    + w2 * fast_tanh(u2 + kv.z) + w3 * fast_tanh(u3 + kv.w);
            }
            s_sc[0][k] = a0;
            s_sc[1][k] = a1;
        }
    }
    __syncthreads();

    // ---- softmax over k < valid; wave w: row r = w&1, k-half = w>>1 ----
    const int wv_ = t >> 6, lane = t & 63;
    const int r = wv_ & 1, half = wv_ >> 1;
    const int kend = min(valid, half * 512 + 512);

    float lmax = -INFINITY;
    for (int k = half * 512 + lane; k < kend; k += 64) lmax = fmaxf(lmax, s_sc[r][k]);
#pragma unroll
    for (int off = 32; off > 0; off >>= 1) lmax = fmaxf(lmax, __shfl_xor(lmax, off, 64));
    if (lane == 0) s_red[wv_] = lmax;
    __syncthreads();
    const float m = fmaxf(s_red[r], s_red[r + 2]);

    const float l2e = 1.4426950408889634f;
    float lsum = 0.f;
    for (int k = half * 512 + lane; k < kend; k += 64) {
        float e = __builtin_amdgcn_exp2f((s_sc[r][k] - m) * l2e);
        s_e[k][r] = e;
        lsum += e;
    }
#pragma unroll
    for (int off = 32; off > 0; off >>= 1) lsum += __shfl_xor(lsum, off, 64);
    if (lane == 0) s_sum[wv_] = lsum;
    __syncthreads();
    if (t < 2) s_inv[t] = 1.0f / (s_sum[t] + s_sum[t + 2]);
    __syncthreads();

    // ---- AV: thread = (v-quad, k-slice); coalesced values float4, broadcast e b64 ----
    const int vg = t & 63, ks = t >> 6;
    const int v4 = vg * 4;
    float4 acc0 = {0.f, 0.f, 0.f, 0.f};
    float4 acc1 = {0.f, 0.f, 0.f, 0.f};
    const int kbeg = ks * 256, kstop = min(valid, kbeg + 256);
    const float* vb = values + (size_t)b * KN * DIN;
    for (int k = kbeg; k < kstop; k++) {
        float2 e2 = *(const float2*)&s_e[k][0];
        float4 vvv = *(const float4*)(vb + (size_t)k * DIN + v4);
        acc0.x += e2.x * vvv.x; acc0.y += e2.x * vvv.y;
        acc0.z += e2.x * vvv.z; acc0.w += e2.x * vvv.w;
        acc1.x += e2.y * vvv.x; acc1.y += e2.y * vvv.y;
        acc1.z += e2.y * vvv.z; acc1.w += e2.y * vvv.w;
    }
    *(float4*)&s_part[ks][0][v4] = acc0;
    *(float4*)&s_part[ks][1][v4] = acc1;
    __syncthreads();

#pragma unroll
    for (int of = t; of < 2 * DIN; of += 256) {
        int q = of >> 8, v = of & 255;
        float s = s_part[0][q][v] + s_part[1][q][v] + s_part[2][q][v] + s_part[3][q][v];
        out[(size_t)(b * QN + q0 + q) * DIN + v] = s * s_inv[q];
    }
}

extern "C" void kernel_launch(void* const* d_in, const int* in_sizes, int n_in,
                              void* d_out, int out_size, void* d_ws, size_t ws_size,
                              hipStream_t stream) {
    const float* queries    = (const float*)d_in[0];
    const float* keys       = (const float*)d_in[1];
    const float* values     = (const float*)d_in[2];
    const int*   valid_lens = (const int*)d_in[3];
    const float* W_q        = (const float*)d_in[4];
    const float* W_k        = (const float*)d_in[5];
    const float* w_v        = (const float*)d_in[6];
    float* out = (float*)d_out;

    float* qp = (float*)d_ws;                      // [B*QN, 128]
    float* kp = qp + (size_t)BQ * QN * HD;         // [B*KN, 128]

    proj_kernel<<<(BQ * QN + BQ * KN) / 16, 256, 0, stream>>>(queries, keys, W_q, W_k, qp, kp);
    attn_kernel<<<BQ * QN / 2, 256, 0, stream>>>(qp, kp, values, valid_lens, w_v, out);
}